// Round 6
// baseline (178.634 us; speedup 1.0000x reference)
//
#include <hip/hip_runtime.h>

namespace {

constexpr int L = 3264;
constexpr int K = 12;
constexpr int S = 8;
constexpr int B = 64;
constexpr int A = 4;
constexpr int R = 816;            // L / LOCC
constexpr int NOFF = 21;          // delays -10..10
constexpr int PEAK_STEP = L / K;  // 272
constexpr float TWO_PI = 6.28318530717958647692f;
constexpr float CINV = TWO_PI / (float)L;
constexpr int NCHUNK = (L + 255) / 256;  // 13
constexpr int HS_MAX = 66;        // max havg slice entries per chunk

__device__ __forceinline__ float rfl(float x) {
    return __uint_as_float(__builtin_amdgcn_readfirstlane(__float_as_uint(x)));
}

// ---------------------------------------------------------------------------
// Kernel 0: twiddle table tw[j] = e^{+i*2*pi*j/L} (26 KB in workspace).
// ---------------------------------------------------------------------------
__global__ __launch_bounds__(256)
void k_table(float2* __restrict__ tw)
{
    const int j = blockIdx.x * 256 + threadIdx.x;
    if (j < L) {
        float sv, cv;
        __sincosf(CINV * (float)j, &sv, &cv);
        tw[j] = make_float2(cv, sv);
    }
}

// ---------------------------------------------------------------------------
// DFT of one LS row at NB consecutive bins starting at idx0d0.
// Register phasors rotated by block-uniform per-bin SGPR steps; explicit
// software prefetch of the next k-iteration's two scalar loads.
// Arithmetic identical (per bin) to the 21-bin version: same k-partition
// (tid stride 256, 12 iters + tail<192), same shuffle-reduce order.
// ---------------------------------------------------------------------------
template <int NB>
__device__ __forceinline__ void dft_bins(
    const float* __restrict__ pr, const float* __restrict__ pi_,
    int idx0d0, int tid, int lane, int w, float2 (*red)[11])
{
    // initial phasors w_d = e^{i*2pi*tid*(idx0d0+d)/L}
    const int jb = (tid * idx0d0) % L;                 // <= 832K
    float br, bi; __sincosf(CINV * (float)jb, &bi, &br);
    float lr, li; __sincosf(CINV * (float)tid, &li, &lr);
    float pwr[NB], pwi[NB], ar[NB], ai[NB];
    pwr[0] = br; pwi[0] = bi;
    #pragma unroll
    for (int d = 1; d < NB; ++d) {
        pwr[d] = pwr[d-1] * lr - pwi[d-1] * li;
        pwi[d] = pwr[d-1] * li + pwi[d-1] * lr;
    }
    #pragma unroll
    for (int d = 0; d < NB; ++d) { ar[d] = 0.f; ai[d] = 0.f; }

    // per-bin k-stride-256 steps — block-uniform -> SGPR
    const int js = (256 * idx0d0) % L;
    float s0r, s0i; __sincosf(CINV * (float)js, &s0i, &s0r);
    float c8r, c8i; __sincosf(CINV * 256.0f, &c8i, &c8r);
    float str_[NB], sti_[NB];
    {
        float cr = s0r, ci = s0i;
        #pragma unroll
        for (int d = 0; d < NB; ++d) {
            str_[d] = rfl(cr); sti_[d] = rfl(ci);
            const float nr2 = cr * c8r - ci * c8i;
            ci = cr * c8i + ci * c8r;
            cr = nr2;
        }
    }

    float xr = pr[tid], xi = pi_[tid];
    for (int it = 0; it < 12; ++it) {
        // prefetch next sample (incl. the tail sample at it==11)
        float nxr = 0.f, nxi = 0.f;
        if (it < 11) {
            nxr = pr[tid + ((it + 1) << 8)];
            nxi = pi_[tid + ((it + 1) << 8)];
        } else if (tid < 192) {
            nxr = pr[tid + 3072];
            nxi = pi_[tid + 3072];
        }
        #pragma unroll
        for (int d = 0; d < NB; ++d) {
            ar[d] += xr * pwr[d] - xi * pwi[d];
            ai[d] += xr * pwi[d] + xi * pwr[d];
            const float nr2 = pwr[d] * str_[d] - pwi[d] * sti_[d];
            pwi[d] = pwr[d] * sti_[d] + pwi[d] * str_[d];
            pwr[d] = nr2;
        }
        xr = nxr; xi = nxi;
    }
    if (tid < 192) {                                   // tail k = tid + 3072
        #pragma unroll
        for (int d = 0; d < NB; ++d) {
            ar[d] += xr * pwr[d] - xi * pwi[d];
            ai[d] += xr * pwi[d] + xi * pwr[d];
        }
    }

    #pragma unroll
    for (int d = 0; d < NB; ++d) {
        float r = ar[d], im = ai[d];
        #pragma unroll
        for (int o = 32; o > 0; o >>= 1) {
            r  += __shfl_xor(r, o);
            im += __shfl_xor(im, o);
        }
        if (lane == 0) red[w][d] = make_float2(r, im);
    }
}

// ---------------------------------------------------------------------------
// Kernel 1a: 2 blocks per LS row (bins 0-9 / 10-20) -> 4096 blocks.
// ---------------------------------------------------------------------------
__global__ __launch_bounds__(256)
void k_dft(const float* __restrict__ lsr, const float* __restrict__ lsi,
           const int* __restrict__ cs, float* __restrict__ pow_out)
{
    __shared__ float2 red[4][11];

    const int blk = blockIdx.x;
    const int row = blk >> 1;              // sb*A + a
    const int half = blk & 1;
    const int sb = row >> 2;
    const int a = row & 3;
    const int s = sb >> 6;
    const int tid = threadIdx.x;
    const int lane = tid & 63;
    const int w = tid >> 6;

    const int ideal = ((K - cs[s]) % K) * PEAK_STEP;
    int idx0 = (ideal - 10) % L; if (idx0 < 0) idx0 += L;
    const int d0 = half ? 10 : 0;
    const int idx0d0 = (idx0 + d0) % L;

    const float* __restrict__ pr  = lsr + (size_t)row * L;
    const float* __restrict__ pi_ = lsi + (size_t)row * L;

    if (half) dft_bins<11>(pr, pi_, idx0d0, tid, lane, w, red);
    else      dft_bins<10>(pr, pi_, idx0d0, tid, lane, w, red);
    __syncthreads();

    const int NB = half ? 11 : 10;
    if (w == 0 && lane < NB) {
        float rr = 0.f, ii = 0.f;
        #pragma unroll
        for (int q = 0; q < 4; ++q) { rr += red[q][lane].x; ii += red[q][lane].y; }
        pow_out[sb * (NOFF * A) + (d0 + lane) * A + a] = rr * rr + ii * ii;
    }
}

// ---------------------------------------------------------------------------
// Kernel 1b: per sb: sum antenna powers, first-max argmax (jnp semantics).
// ---------------------------------------------------------------------------
__global__ __launch_bounds__(64)
void k_argmax(const float* __restrict__ pow_in, const int* __restrict__ cs,
              int* __restrict__ toff_out, int* __restrict__ m_out)
{
    const int sb = blockIdx.x;
    const int lane = threadIdx.x;
    const int s = sb >> 6;
    const int ideal = ((K - cs[s]) % K) * PEAK_STEP;

    float pw = -1.f;
    if (lane < NOFF) {
        const float4 p4 = *(const float4*)(pow_in + sb * (NOFF * A) + lane * A);
        pw = p4.x + p4.y + p4.z + p4.w;
    }
    float mx = pw;
    #pragma unroll
    for (int o = 32; o > 0; o >>= 1) mx = fmaxf(mx, __shfl_xor(mx, o));
    const unsigned long long msk = __ballot(pw == mx);
    const int argd = __ffsll(msk) - 1;     // lowest lane = first max
    if (lane == 0) {
        const int toff = argd - 10;
        toff_out[sb] = toff;
        m_out[sb]    = toff + ideal;
    }
}

// ---------------------------------------------------------------------------
// Kernel 2: per (b,a,chunk). Fuses h_avg recompute (the <=66-entry slice this
// chunk needs, per stream) into LDS, then interp + residual + timing recovery.
// Twiddle phasors from the LDS table (exact integer phase index) — zero trig.
// ---------------------------------------------------------------------------
__global__ __launch_bounds__(256)
void k_final(const float* __restrict__ lsr, const float* __restrict__ lsi,
             const int* __restrict__ toff_arr, const int* __restrict__ m_arr,
             const float2* __restrict__ tw, float* __restrict__ out)
{
    __shared__ float2 twl[L];              // 26112 B
    __shared__ float2 hs[S][HS_MAX];       // 4224 B
    __shared__ int mps[S], tfs[S];

    const int bid = blockIdx.x;
    const int chunk = bid % NCHUNK;
    const int ba = bid / NCHUNK;
    const int b = ba >> 2;
    const int a = ba & 3;
    const int tid = threadIdx.x;

    for (int j = tid; j < L; j += 256) twl[j] = tw[j];
    if (tid < S) {
        int mp = m_arr[tid * B + b] % L; if (mp < 0) mp += L;
        mps[tid] = mp;
        int tp = toff_arr[tid * B + b] % L; if (tp < 0) tp += L;
        tfs[tid] = tp;
    }
    __syncthreads();

    const int imin = max(0, chunk * 64 - 1);
    const int imax = min(R - 1, chunk * 64 + 64);
    const int cnt = imax - imin + 1;       // <= 66

    // recompute this chunk's h_avg slice: identical formula to the old k_havg
    for (int t = tid; t < S * HS_MAX; t += 256) {
        const int s = t / HS_MAX;
        const int ii = t % HS_MAX;
        if (ii < cnt) {
            const int i = imin + ii;
            const int sb = s * B + b;
            const int mp = mps[s];
            const float2 emp = twl[mp];
            const float2 w0 = twl[(mp * (4 * i)) % L];   // <= 10.6M, int32 ok
            const float4 xr = *(const float4*)(lsr + ((size_t)sb * A + a) * L + 4 * i);
            const float4 xi = *(const float4*)(lsi + ((size_t)sb * A + a) * L + 4 * i);
            float wr = w0.x, wi = w0.y;
            float are, aim, nr;
            are  = xr.x * wr - xi.x * wi;  aim  = xr.x * wi + xi.x * wr;
            nr = wr * emp.x - wi * emp.y;  wi = wr * emp.y + wi * emp.x;  wr = nr;
            are += xr.y * wr - xi.y * wi;  aim += xr.y * wi + xi.y * wr;
            nr = wr * emp.x - wi * emp.y;  wi = wr * emp.y + wi * emp.x;  wr = nr;
            are += xr.z * wr - xi.z * wi;  aim += xr.z * wi + xi.z * wr;
            nr = wr * emp.x - wi * emp.y;  wi = wr * emp.y + wi * emp.x;  wr = nr;
            are += xr.w * wr - xi.w * wi;  aim += xr.w * wi + xi.w * wr;
            hs[s][ii] = make_float2(are * 0.25f, aim * 0.25f);
        }
    }
    __syncthreads();

    const int l = chunk * 256 + tid;
    if (l >= L) return;

    float t2 = ((float)l - 1.5f) * 0.25f;
    t2 = fminf(fmaxf(t2, 0.0f), (float)(R - 1));
    const int i0 = (int)t2;
    const int i1 = min(i0 + 1, R - 1);
    const float frac = t2 - (float)i0;

    float hire[S], hiim[S], pmre[S], pmim[S];
    float rre = 0.f, rim = 0.f;

    #pragma unroll
    for (int s = 0; s < S; ++s) {
        const float2 wm = twl[(mps[s] * l) % L];       // <= 10.65M, int32 ok
        const float2 h0 = hs[s][i0 - imin];
        const float2 h1 = hs[s][i1 - imin];
        const float hr = h0.x * (1.f - frac) + h1.x * frac;
        const float hi = h0.y * (1.f - frac) + h1.y * frac;
        hire[s] = hr; hiim[s] = hi; pmre[s] = wm.x; pmim[s] = wm.y;
        rre += hr * wm.x + hi * wm.y;                  // h * conj(ph_m)
        rim += hi * wm.x - hr * wm.y;
    }

    const size_t off0 = ((size_t)(b * A + a)) * L + l;
    const float resre = lsr[off0] - rre;
    const float resim = lsi[off0] - rim;

    #pragma unroll
    for (int s = 0; s < S; ++s) {
        const float wre = hire[s] + resre * pmre[s] - resim * pmim[s];
        const float wim = hiim[s] + resre * pmim[s] + resim * pmre[s];
        const float2 wt = twl[(tfs[s] * l) % L];
        const float fre = wre * wt.x + wim * wt.y;     // * conj(ph_T)
        const float fim = wim * wt.x - wre * wt.y;
        const size_t o = (((size_t)(s * B + b)) * A + a) * L + l;
        __builtin_nontemporal_store(fre, &out[o]);
        __builtin_nontemporal_store(fim, &out[(size_t)S * B * A * L + o]);
    }
}

}  // namespace

extern "C" void kernel_launch(void* const* d_in, const int* in_sizes, int n_in,
                              void* d_out, int out_size, void* d_ws, size_t ws_size,
                              hipStream_t stream) {
    (void)in_sizes; (void)n_in; (void)out_size; (void)ws_size;
    const float* lsr = (const float*)d_in[0];
    const float* lsi = (const float*)d_in[1];
    const int*   cs  = (const int*)d_in[2];
    // d_in[3] (noise_powers) unused: mmse_module is identity.

    int* toff = (int*)d_ws;                                  // 512 ints @ 0
    int* marr = toff + 512;                                  // 512 ints @ 2048
    float2* tw   = (float2*)((char*)d_ws + 4096);            // 26112 B
    float*  powb = (float*)((char*)d_ws + 30720);            // 512*84*4 B

    k_table <<<NCHUNK, 256, 0, stream>>>(tw);
    k_dft   <<<S * B * A * 2, 256, 0, stream>>>(lsr, lsi, cs, powb);
    k_argmax<<<S * B, 64, 0, stream>>>(powb, cs, toff, marr);
    k_final <<<B * A * NCHUNK, 256, 0, stream>>>(lsr, lsi, toff, marr, tw,
                                                 (float*)d_out);
}